// Round 15
// baseline (278.679 us; speedup 1.0000x reference)
//
#include <hip/hip_runtime.h>
#include <hip/hip_fp16.h>

#define N_NODES 100000
#define N_EDGES 1600000
#define BSHIFT 9
#define NBUCK ((N_NODES + 511) / 512)   // 196 coarse buckets of 512 nodes
#define BCAP 12288                      // per-bucket capacity (mean 8163, ~45 sigma)

// ---------------------------------------------------------------------------
// phase 1: bucket edges by dst>>9. Entry packed: src | (dst&511)<<17.
__global__ void bucket1_kernel(const int* __restrict__ src, const int* __restrict__ dst,
                               int* __restrict__ gbcount, int* __restrict__ bbuf, int E) {
    __shared__ int hcnt[NBUCK];
    __shared__ int hbase[NBUCK];
    int t = threadIdx.x;
    for (int i = t; i < NBUCK; i += 256) hcnt[i] = 0;
    __syncthreads();
    int e0 = blockIdx.x * 2048 + t;
    int ss[8], dd[8];
#pragma unroll
    for (int u = 0; u < 8; u++) {
        int e = e0 + u * 256;
        if (e < E) {
            ss[u] = src[e];
            dd[u] = dst[e];
            atomicAdd(&hcnt[dd[u] >> BSHIFT], 1);
        } else {
            dd[u] = -1;
        }
    }
    __syncthreads();
    for (int i = t; i < NBUCK; i += 256) {
        int c = hcnt[i];
        hbase[i] = c ? atomicAdd(&gbcount[i], c) : 0;
        hcnt[i] = 0;   // reuse as local cursor
    }
    __syncthreads();
#pragma unroll
    for (int u = 0; u < 8; u++) {
        if (dd[u] >= 0) {
            int bk = dd[u] >> BSHIFT;
            int r = atomicAdd(&hcnt[bk], 1);
            bbuf[(size_t)bk * BCAP + hbase[bk] + r] = ss[u] | ((dd[u] & 511) << 17);
        }
    }
}

// --- exclusive scan of the 196 bucket sizes -> bucket bases; rowptr[N]=E ----
__global__ void scan196_kernel(const int* __restrict__ gbcount, int* __restrict__ gbase,
                               int* __restrict__ rowptrN, int E) {
    __shared__ int s[256];
    int t = threadIdx.x;
    int v = (t < NBUCK) ? gbcount[t] : 0;
    s[t] = v;
    __syncthreads();
    for (int off = 1; off < 256; off <<= 1) {
        int u = (t >= off) ? s[t - off] : 0;
        __syncthreads();
        s[t] += u;
        __syncthreads();
    }
    if (t < NBUCK) gbase[t] = s[t] - v;
    if (t == 0) *rowptrN = E;
}

// --- phase 2 (fused hist+scan+dinv+scatter): one 512-thread block per bucket.
__global__ __launch_bounds__(512)
void bucket2_kernel(const int* __restrict__ bbuf, const int* __restrict__ gbcount,
                    const int* __restrict__ gbase, int* __restrict__ rowptr,
                    float* __restrict__ dinv, int* __restrict__ eidx, int N) {
    int b = blockIdx.x;
    int base_node = b << BSHIFT;
    int nn = min(512, N - base_node);
    int t = threadIdx.x;
    __shared__ int s[512];
    __shared__ int cur[512];
    s[t] = 0;
    __syncthreads();
    int sz = gbcount[b];
    const int* eb = bbuf + (size_t)b * BCAP;
    for (int j = t; j < sz; j += 512) atomicAdd(&s[((unsigned)eb[j]) >> 17], 1);
    __syncthreads();
    int myc = s[t];
    if (t < nn) dinv[base_node + t] = rsqrtf((float)myc + 1.0f);
    __syncthreads();
    for (int off = 1; off < 512; off <<= 1) {
        int u = (t >= off) ? s[t - off] : 0;
        __syncthreads();
        s[t] += u;
        __syncthreads();
    }
    int rp = gbase[b] + s[t] - myc;      // exclusive
    if (t < nn) rowptr[base_node + t] = rp;
    cur[t] = rp;
    __syncthreads();
    for (int j = t; j < sz; j += 512) {
        int e = eb[j];
        int pos = atomicAdd(&cur[((unsigned)e) >> 17], 1);
        eidx[pos] = e & 0x1FFFF;
    }
}

// --- determinism: canonicalize each row (sort ascending). One WAVE per row. --
__global__ void sortrow_wave(const int* __restrict__ rowptr, int* __restrict__ eidx, int n) {
    int g = (blockIdx.x * blockDim.x + threadIdx.x) >> 6;
    int lane = threadIdx.x & 63;
    if (g >= n) return;
    int start = rowptr[g];
    int end = rowptr[g + 1];
    int len = end - start;
    if (len <= 1) return;

    if (len <= 64) {
        int v = (lane < len) ? eidx[start + lane] : 0x7fffffff;
#pragma unroll
        for (int k = 2; k <= 64; k <<= 1) {
#pragma unroll
            for (int j = k >> 1; j > 0; j >>= 1) {
                int partner = __shfl_xor(v, j, 64);
                bool up = ((lane & k) == 0);
                bool keepMin = (((lane & j) == 0) == up);
                int mn = min(v, partner), mx = max(v, partner);
                v = keepMin ? mn : mx;
            }
        }
        if (lane < len) eidx[start + lane] = v;
    } else if (lane == 0) {
        for (int i = start + 1; i < end; i++) {
            int key = eidx[i];
            int j = i - 1;
            while (j >= start && eidx[j] > key) { eidx[j + 1] = eidx[j]; j--; }
            eidx[j + 1] = key;
        }
    }
}

// ---------------------------------------------------------------------------
// LDS-tiled GEMM (layer 1 only), 4x4 register blocking, epilogue = dinv*fp16.
template <int FIN, int FOUT>
__global__ __launch_bounds__(256, 2)
void gemm_tiled(const float* __restrict__ in, const float* __restrict__ W,
                const float* __restrict__ dinv, __half* __restrict__ out, int n) {
    constexpr int CG = FOUT / 4;
    constexpr int RG = 256 / CG;
    constexpr int TR = RG * 4;
    constexpr int LDA = FIN + 4;
    __shared__ float sIn[TR * LDA];
    __shared__ float sW[FIN * FOUT];

    for (int i = threadIdx.x; i < FIN * FOUT / 4; i += 256)
        ((float4*)sW)[i] = ((const float4*)W)[i];

    int r0 = blockIdx.x * TR;
    for (int i = threadIdx.x; i < TR * FIN / 4; i += 256) {
        int rr = i / (FIN / 4);
        int cc = i % (FIN / 4);
        int gr = r0 + rr;
        float4 v = (gr < n) ? ((const float4*)in)[(size_t)gr * (FIN / 4) + cc]
                            : make_float4(0.f, 0.f, 0.f, 0.f);
        *(float4*)&sIn[rr * LDA + cc * 4] = v;
    }
    __syncthreads();

    int tc = threadIdx.x % CG;
    int tr = threadIdx.x / CG;
    int rbase = tr * 4, cbase = tc * 4;
    float acc[4][4] = {};

#pragma unroll 2
    for (int k = 0; k < FIN; k += 4) {
        float4 a[4], b[4];
#pragma unroll
        for (int i = 0; i < 4; i++) a[i] = *(float4*)&sIn[(rbase + i) * LDA + k];
#pragma unroll
        for (int kk = 0; kk < 4; kk++) b[kk] = *(float4*)&sW[(k + kk) * FOUT + cbase];
#pragma unroll
        for (int i = 0; i < 4; i++) {
            acc[i][0] += a[i].x * b[0].x + a[i].y * b[1].x + a[i].z * b[2].x + a[i].w * b[3].x;
            acc[i][1] += a[i].x * b[0].y + a[i].y * b[1].y + a[i].z * b[2].y + a[i].w * b[3].y;
            acc[i][2] += a[i].x * b[0].z + a[i].y * b[1].z + a[i].z * b[2].z + a[i].w * b[3].z;
            acc[i][3] += a[i].x * b[0].w + a[i].y * b[1].w + a[i].z * b[2].w + a[i].w * b[3].w;
        }
    }

#pragma unroll
    for (int i = 0; i < 4; i++) {
        int gr = r0 + rbase + i;
        if (gr < n) {
            float dv = dinv[gr];
            union { __half h[4]; uint2 u; } pk;
            pk.h[0] = __float2half_rn(dv * acc[i][0]);
            pk.h[1] = __float2half_rn(dv * acc[i][1]);
            pk.h[2] = __float2half_rn(dv * acc[i][2]);
            pk.h[3] = __float2half_rn(dv * acc[i][3]);
            *(uint2*)&out[(size_t)gr * FOUT + cbase] = pk.u;
        }
    }
}

// ---------------------------------------------------------------------------
// FUSED aggregation + next-layer matvec. sv stride = FIN+1: with stride FIN
// the matvec read sv[slot*FIN+k] hit bank k%32 for all 8 slots (8-way
// conflict, 2.6M counted in R14); +1 makes banks (slot+k)%32 — conflict-free.
// __launch_bounds__(256,8): 48 VGPR < 64 cap, ~17KB LDS -> 8 blocks/CU.
template <int FIN, int FOUT, bool OUT_HALF>
__global__ __launch_bounds__(256, 8)
void agg_gemm_kernel(const int* __restrict__ eidx, const int* __restrict__ rowptr,
                     const float* __restrict__ dinv, const __half* __restrict__ h,
                     const float* __restrict__ bias, const float* __restrict__ W,
                     void* __restrict__ outv, int n) {
    constexpr int L = 8;                 // lanes per node
    constexpr int PH = FIN / L;          // halves per lane (8 or 4)
    constexpr int NODES = 256 / L;       // 32 nodes per block
    constexpr int SVS = FIN + 1;         // padded sv stride (bank-conflict fix)
    using vh = _Float16 __attribute__((ext_vector_type(PH)));
    __shared__ float sW[FIN * FOUT];
    __shared__ float sv[NODES * SVS];

    for (int i = threadIdx.x; i < FIN * FOUT / 4; i += 256)
        ((float4*)sW)[i] = ((const float4*)W)[i];

    int g = (blockIdx.x * blockDim.x + threadIdx.x) / L;
    int lane = threadIdx.x % L;
    int slot = threadIdx.x / L;          // node slot in block
    float di = 0.f;

    if (g < n) {
        int j = rowptr[g];
        int end = rowptr[g + 1];
        di = dinv[g];
        const __half* hb = h + lane * PH;

        float acc0[PH], acc1[PH];
#pragma unroll
        for (int q = 0; q < PH; q++) { acc0[q] = 0.f; acc1[q] = 0.f; }

        for (; j + 8 <= end; j += 8) {
            int s0 = eidx[j];
            int s1 = eidx[j + 1];
            int s2 = eidx[j + 2];
            int s3 = eidx[j + 3];
            int s4 = eidx[j + 4];
            int s5 = eidx[j + 5];
            int s6 = eidx[j + 6];
            int s7 = eidx[j + 7];
            vh v0 = *(const vh*)(hb + (size_t)s0 * FIN);
            vh v1 = *(const vh*)(hb + (size_t)s1 * FIN);
            vh v2 = *(const vh*)(hb + (size_t)s2 * FIN);
            vh v3 = *(const vh*)(hb + (size_t)s3 * FIN);
            vh v4 = *(const vh*)(hb + (size_t)s4 * FIN);
            vh v5 = *(const vh*)(hb + (size_t)s5 * FIN);
            vh v6 = *(const vh*)(hb + (size_t)s6 * FIN);
            vh v7 = *(const vh*)(hb + (size_t)s7 * FIN);
#pragma unroll
            for (int q = 0; q < PH; q++) {
                acc0[q] += (float)v0[q] + (float)v2[q];
                acc1[q] += (float)v1[q] + (float)v3[q];
                acc0[q] += (float)v4[q] + (float)v6[q];
                acc1[q] += (float)v5[q] + (float)v7[q];
            }
        }
        for (; j + 2 <= end; j += 2) {
            int s0 = eidx[j];
            int s1 = eidx[j + 1];
            vh v0 = *(const vh*)(hb + (size_t)s0 * FIN);
            vh v1 = *(const vh*)(hb + (size_t)s1 * FIN);
#pragma unroll
            for (int q = 0; q < PH; q++) { acc0[q] += (float)v0[q]; acc1[q] += (float)v1[q]; }
        }
        if (j < end) {
            vh v = *(const vh*)(hb + (size_t)eidx[j] * FIN);
#pragma unroll
            for (int q = 0; q < PH; q++) acc0[q] += (float)v[q];
        }

        vh sf = *(const vh*)(hb + (size_t)g * FIN);
        float* svn = &sv[slot * SVS + lane * PH];
#pragma unroll
        for (int q = 0; q < PH; q++) {
            float v = di * ((acc0[q] + acc1[q]) + (float)sf[q]) + bias[lane * PH + q];
            svn[q] = fmaxf(v, 0.f);      // relu
        }
    }
    __syncthreads();                     // sW loaded + sv written

    if (g < n) {
        const float* vn = &sv[slot * SVS];
        if constexpr (OUT_HALF) {
            // FOUT=32: lane owns 4 output cols
            constexpr int PC = FOUT / L;
            float o[PC] = {};
            for (int k = 0; k < FIN; k++) {
                float vk = vn[k];
                float4 w = *(const float4*)&sW[k * FOUT + lane * PC];
                o[0] += vk * w.x; o[1] += vk * w.y; o[2] += vk * w.z; o[3] += vk * w.w;
            }
            union { __half h[4]; uint2 u; } pk;
#pragma unroll
            for (int q = 0; q < PC; q++) pk.h[q] = __float2half_rn(di * o[q]);
            *(uint2*)((__half*)outv + (size_t)g * FOUT + lane * PC) = pk.u;
        } else {
            // FOUT=2: lanes 0/1 each compute one fp32 output
            if (lane < FOUT) {
                float o = 0.f;
                for (int k = 0; k < FIN; k++) o += vn[k] * sW[k * FOUT + lane];
                ((float*)outv)[(size_t)g * FOUT + lane] = di * o;
            }
        }
    }
}

// fp32 scalar-gather agg for the final layer (F=2), bias, no relu
template <int F>
__global__ void agg_kernel(const int* __restrict__ eidx, const int* __restrict__ rowptr,
                           const float* __restrict__ dinv, const float* __restrict__ h,
                           const float* __restrict__ b, float* __restrict__ out, int n) {
    int g = (blockIdx.x * blockDim.x + threadIdx.x) / F;
    int lane = threadIdx.x % F;
    if (g >= n) return;
    int j = rowptr[g];
    int end = rowptr[g + 1];
    float di = dinv[g];
    float hs = h[(size_t)g * F + lane];

    float acc0 = 0.f, acc1 = 0.f, acc2 = 0.f, acc3 = 0.f;
    float acc4 = 0.f, acc5 = 0.f, acc6 = 0.f, acc7 = 0.f;
    for (; j + 8 <= end; j += 8) {
        int s0 = eidx[j];
        int s1 = eidx[j + 1];
        int s2 = eidx[j + 2];
        int s3 = eidx[j + 3];
        int s4 = eidx[j + 4];
        int s5 = eidx[j + 5];
        int s6 = eidx[j + 6];
        int s7 = eidx[j + 7];
        acc0 += h[(size_t)s0 * F + lane];
        acc1 += h[(size_t)s1 * F + lane];
        acc2 += h[(size_t)s2 * F + lane];
        acc3 += h[(size_t)s3 * F + lane];
        acc4 += h[(size_t)s4 * F + lane];
        acc5 += h[(size_t)s5 * F + lane];
        acc6 += h[(size_t)s6 * F + lane];
        acc7 += h[(size_t)s7 * F + lane];
    }
    for (; j + 2 <= end; j += 2) {
        int s0 = eidx[j];
        int s1 = eidx[j + 1];
        acc0 += h[(size_t)s0 * F + lane];
        acc1 += h[(size_t)s1 * F + lane];
    }
    if (j < end) {
        acc2 += h[(size_t)eidx[j] * F + lane];
    }
    float acc = ((acc0 + acc1) + (acc2 + acc3)) + ((acc4 + acc5) + (acc6 + acc7));
    out[(size_t)g * F + lane] = di * (acc + hs) + b[lane];
}

// ---------------------------------------------------------------------------
extern "C" void kernel_launch(void* const* d_in, const int* in_sizes, int n_in,
                              void* d_out, int out_size, void* d_ws, size_t ws_size,
                              hipStream_t stream) {
    const float* x  = (const float*)d_in[0];
    const int* ei   = (const int*)d_in[1];
    const float* W1 = (const float*)d_in[2];
    const float* b1 = (const float*)d_in[3];
    const float* W2 = (const float*)d_in[4];
    const float* b2 = (const float*)d_in[5];
    const float* W3 = (const float*)d_in[6];
    const float* b3 = (const float*)d_in[7];
    float* out = (float*)d_out;

    const int N = N_NODES;
    const int E = N_EDGES;
    const int* src = ei;
    const int* dst = ei + E;

    char* p = (char*)d_ws;
    int*    rowptr  = (int*)p;            p += ((size_t)(N + 1) * 4 + 15) / 16 * 16;
    float*  dinv    = (float*)p;          p += ((size_t)N * 4 + 15) / 16 * 16;
    int*    gbcount = (int*)p;            p += ((size_t)NBUCK * 4 + 15) / 16 * 16;
    int*    gbase   = (int*)p;            p += ((size_t)NBUCK * 4 + 15) / 16 * 16;
    int*    eidx    = (int*)p;            p += (size_t)E * 4;
    __half* A1      = (__half*)p;         p += (size_t)N * 64 * 2;
    __half* A2      = (__half*)p;         p += (size_t)N * 32 * 2;
    float*  A3      = (float*)p;          p += (size_t)N * 2 * 4;
    int*    bbuf    = (int*)p;            // 196*12288*4 = 9.6 MB (packed edges)

    const int T = 256;

    // --- build CSR + dinv: bucket -> scan196 -> fused hist/scan/scatter; sort ---
    hipMemsetAsync(gbcount, 0, NBUCK * sizeof(int), stream);
    bucket1_kernel<<<(E + 2047) / 2048, T, 0, stream>>>(src, dst, gbcount, bbuf, E);
    scan196_kernel<<<1, 256, 0, stream>>>(gbcount, gbase, rowptr + N, E);
    bucket2_kernel<<<NBUCK, 512, 0, stream>>>(bbuf, gbcount, gbase, rowptr, dinv, eidx, N);
    sortrow_wave<<<(N * 64 + T - 1) / T, T, 0, stream>>>(rowptr, eidx, N);

    // --- layer 1 GEMM: A1 = fp16(dinv * (x @ W1)) ---
    gemm_tiled<64, 64><<<(N + 63) / 64, T, 0, stream>>>(x, W1, dinv, A1, N);

    // --- fused agg1 + gemm2: A2 = fp16(dinv * relu(agg(A1)+b1) @ W2) ---
    agg_gemm_kernel<64, 32, true><<<(N + 31) / 32, T, 0, stream>>>(
        eidx, rowptr, dinv, A1, b1, W2, A2, N);

    // --- fused agg2 + gemm3: A3 = fp32(dinv * relu(agg(A2)+b2) @ W3) ---
    agg_gemm_kernel<32, 2, false><<<(N + 31) / 32, T, 0, stream>>>(
        eidx, rowptr, dinv, A2, b2, W3, A3, N);

    // --- final aggregation: out = dinv*(agg(A3)+self) + b3 ---
    agg_kernel<2><<<(N * 2 + T - 1) / T, T, 0, stream>>>(eidx, rowptr, dinv, A3, b3, out, N);
}

// Round 16
// 266.587 us; speedup vs baseline: 1.0454x; 1.0454x over previous
//
#include <hip/hip_runtime.h>
#include <hip/hip_fp16.h>

#define N_NODES 100000
#define N_EDGES 1600000
#define BSHIFT 9
#define NBUCK ((N_NODES + 511) / 512)   // 196 coarse buckets of 512 nodes
#define BCAP 12288                      // per-bucket capacity (mean 8163, ~45 sigma)

// ---------------------------------------------------------------------------
// phase 1: bucket edges by dst>>9. Entry packed: src | (dst&511)<<17.
__global__ void bucket1_kernel(const int* __restrict__ src, const int* __restrict__ dst,
                               int* __restrict__ gbcount, int* __restrict__ bbuf, int E) {
    __shared__ int hcnt[NBUCK];
    __shared__ int hbase[NBUCK];
    int t = threadIdx.x;
    for (int i = t; i < NBUCK; i += 256) hcnt[i] = 0;
    __syncthreads();
    int e0 = blockIdx.x * 2048 + t;
    int ss[8], dd[8];
#pragma unroll
    for (int u = 0; u < 8; u++) {
        int e = e0 + u * 256;
        if (e < E) {
            ss[u] = src[e];
            dd[u] = dst[e];
            atomicAdd(&hcnt[dd[u] >> BSHIFT], 1);
        } else {
            dd[u] = -1;
        }
    }
    __syncthreads();
    for (int i = t; i < NBUCK; i += 256) {
        int c = hcnt[i];
        hbase[i] = c ? atomicAdd(&gbcount[i], c) : 0;
        hcnt[i] = 0;   // reuse as local cursor
    }
    __syncthreads();
#pragma unroll
    for (int u = 0; u < 8; u++) {
        if (dd[u] >= 0) {
            int bk = dd[u] >> BSHIFT;
            int r = atomicAdd(&hcnt[bk], 1);
            bbuf[(size_t)bk * BCAP + hbase[bk] + r] = ss[u] | ((dd[u] & 511) << 17);
        }
    }
}

// --- exclusive scan of the 196 bucket sizes -> bucket bases; rowptr[N]=E ----
__global__ void scan196_kernel(const int* __restrict__ gbcount, int* __restrict__ gbase,
                               int* __restrict__ rowptrN, int E) {
    __shared__ int s[256];
    int t = threadIdx.x;
    int v = (t < NBUCK) ? gbcount[t] : 0;
    s[t] = v;
    __syncthreads();
    for (int off = 1; off < 256; off <<= 1) {
        int u = (t >= off) ? s[t - off] : 0;
        __syncthreads();
        s[t] += u;
        __syncthreads();
    }
    if (t < NBUCK) gbase[t] = s[t] - v;
    if (t == 0) *rowptrN = E;
}

// --- phase 2 (fused hist+scan+dinv+scatter): one 512-thread block per bucket.
__global__ __launch_bounds__(512)
void bucket2_kernel(const int* __restrict__ bbuf, const int* __restrict__ gbcount,
                    const int* __restrict__ gbase, int* __restrict__ rowptr,
                    float* __restrict__ dinv, int* __restrict__ eidx, int N) {
    int b = blockIdx.x;
    int base_node = b << BSHIFT;
    int nn = min(512, N - base_node);
    int t = threadIdx.x;
    __shared__ int s[512];
    __shared__ int cur[512];
    s[t] = 0;
    __syncthreads();
    int sz = gbcount[b];
    const int* eb = bbuf + (size_t)b * BCAP;
    for (int j = t; j < sz; j += 512) atomicAdd(&s[((unsigned)eb[j]) >> 17], 1);
    __syncthreads();
    int myc = s[t];
    if (t < nn) dinv[base_node + t] = rsqrtf((float)myc + 1.0f);
    __syncthreads();
    for (int off = 1; off < 512; off <<= 1) {
        int u = (t >= off) ? s[t - off] : 0;
        __syncthreads();
        s[t] += u;
        __syncthreads();
    }
    int rp = gbase[b] + s[t] - myc;      // exclusive
    if (t < nn) rowptr[base_node + t] = rp;
    cur[t] = rp;
    __syncthreads();
    for (int j = t; j < sz; j += 512) {
        int e = eb[j];
        int pos = atomicAdd(&cur[((unsigned)e) >> 17], 1);
        eidx[pos] = e & 0x1FFFF;
    }
}

// --- determinism: canonicalize each row (sort ascending). One WAVE per row. --
__global__ void sortrow_wave(const int* __restrict__ rowptr, int* __restrict__ eidx, int n) {
    int g = (blockIdx.x * blockDim.x + threadIdx.x) >> 6;
    int lane = threadIdx.x & 63;
    if (g >= n) return;
    int start = rowptr[g];
    int end = rowptr[g + 1];
    int len = end - start;
    if (len <= 1) return;

    if (len <= 64) {
        int v = (lane < len) ? eidx[start + lane] : 0x7fffffff;
#pragma unroll
        for (int k = 2; k <= 64; k <<= 1) {
#pragma unroll
            for (int j = k >> 1; j > 0; j >>= 1) {
                int partner = __shfl_xor(v, j, 64);
                bool up = ((lane & k) == 0);
                bool keepMin = (((lane & j) == 0) == up);
                int mn = min(v, partner), mx = max(v, partner);
                v = keepMin ? mn : mx;
            }
        }
        if (lane < len) eidx[start + lane] = v;
    } else if (lane == 0) {
        for (int i = start + 1; i < end; i++) {
            int key = eidx[i];
            int j = i - 1;
            while (j >= start && eidx[j] > key) { eidx[j + 1] = eidx[j]; j--; }
            eidx[j + 1] = key;
        }
    }
}

// ---------------------------------------------------------------------------
// LDS-tiled GEMM (layer 1 only), 4x4 register blocking, epilogue = dinv*fp16.
template <int FIN, int FOUT>
__global__ __launch_bounds__(256, 2)
void gemm_tiled(const float* __restrict__ in, const float* __restrict__ W,
                const float* __restrict__ dinv, __half* __restrict__ out, int n) {
    constexpr int CG = FOUT / 4;
    constexpr int RG = 256 / CG;
    constexpr int TR = RG * 4;
    constexpr int LDA = FIN + 4;
    __shared__ float sIn[TR * LDA];
    __shared__ float sW[FIN * FOUT];

    for (int i = threadIdx.x; i < FIN * FOUT / 4; i += 256)
        ((float4*)sW)[i] = ((const float4*)W)[i];

    int r0 = blockIdx.x * TR;
    for (int i = threadIdx.x; i < TR * FIN / 4; i += 256) {
        int rr = i / (FIN / 4);
        int cc = i % (FIN / 4);
        int gr = r0 + rr;
        float4 v = (gr < n) ? ((const float4*)in)[(size_t)gr * (FIN / 4) + cc]
                            : make_float4(0.f, 0.f, 0.f, 0.f);
        *(float4*)&sIn[rr * LDA + cc * 4] = v;
    }
    __syncthreads();

    int tc = threadIdx.x % CG;
    int tr = threadIdx.x / CG;
    int rbase = tr * 4, cbase = tc * 4;
    float acc[4][4] = {};

#pragma unroll 2
    for (int k = 0; k < FIN; k += 4) {
        float4 a[4], b[4];
#pragma unroll
        for (int i = 0; i < 4; i++) a[i] = *(float4*)&sIn[(rbase + i) * LDA + k];
#pragma unroll
        for (int kk = 0; kk < 4; kk++) b[kk] = *(float4*)&sW[(k + kk) * FOUT + cbase];
#pragma unroll
        for (int i = 0; i < 4; i++) {
            acc[i][0] += a[i].x * b[0].x + a[i].y * b[1].x + a[i].z * b[2].x + a[i].w * b[3].x;
            acc[i][1] += a[i].x * b[0].y + a[i].y * b[1].y + a[i].z * b[2].y + a[i].w * b[3].y;
            acc[i][2] += a[i].x * b[0].z + a[i].y * b[1].z + a[i].z * b[2].z + a[i].w * b[3].z;
            acc[i][3] += a[i].x * b[0].w + a[i].y * b[1].w + a[i].z * b[2].w + a[i].w * b[3].w;
        }
    }

#pragma unroll
    for (int i = 0; i < 4; i++) {
        int gr = r0 + rbase + i;
        if (gr < n) {
            float dv = dinv[gr];
            union { __half h[4]; uint2 u; } pk;
            pk.h[0] = __float2half_rn(dv * acc[i][0]);
            pk.h[1] = __float2half_rn(dv * acc[i][1]);
            pk.h[2] = __float2half_rn(dv * acc[i][2]);
            pk.h[3] = __float2half_rn(dv * acc[i][3]);
            *(uint2*)&out[(size_t)gr * FOUT + cbase] = pk.u;
        }
    }
}

// ---------------------------------------------------------------------------
// FUSED aggregation + next-layer matvec. sv stride = FIN+1 (bank-conflict fix,
// R14: 2.6M conflicts -> R15: 200k). __launch_bounds__(256,4): VGPR 48, no
// spill — R15's (256,8) forced VGPR=32 and spilled 41 MB to scratch.
template <int FIN, int FOUT, bool OUT_HALF>
__global__ __launch_bounds__(256, 4)
void agg_gemm_kernel(const int* __restrict__ eidx, const int* __restrict__ rowptr,
                     const float* __restrict__ dinv, const __half* __restrict__ h,
                     const float* __restrict__ bias, const float* __restrict__ W,
                     void* __restrict__ outv, int n) {
    constexpr int L = 8;                 // lanes per node
    constexpr int PH = FIN / L;          // halves per lane (8 or 4)
    constexpr int NODES = 256 / L;       // 32 nodes per block
    constexpr int SVS = FIN + 1;         // padded sv stride (bank-conflict fix)
    using vh = _Float16 __attribute__((ext_vector_type(PH)));
    __shared__ float sW[FIN * FOUT];
    __shared__ float sv[NODES * SVS];

    for (int i = threadIdx.x; i < FIN * FOUT / 4; i += 256)
        ((float4*)sW)[i] = ((const float4*)W)[i];

    int g = (blockIdx.x * blockDim.x + threadIdx.x) / L;
    int lane = threadIdx.x % L;
    int slot = threadIdx.x / L;          // node slot in block
    float di = 0.f;

    if (g < n) {
        int j = rowptr[g];
        int end = rowptr[g + 1];
        di = dinv[g];
        const __half* hb = h + lane * PH;

        float acc0[PH], acc1[PH];
#pragma unroll
        for (int q = 0; q < PH; q++) { acc0[q] = 0.f; acc1[q] = 0.f; }

        for (; j + 8 <= end; j += 8) {
            int s0 = eidx[j];
            int s1 = eidx[j + 1];
            int s2 = eidx[j + 2];
            int s3 = eidx[j + 3];
            int s4 = eidx[j + 4];
            int s5 = eidx[j + 5];
            int s6 = eidx[j + 6];
            int s7 = eidx[j + 7];
            vh v0 = *(const vh*)(hb + (size_t)s0 * FIN);
            vh v1 = *(const vh*)(hb + (size_t)s1 * FIN);
            vh v2 = *(const vh*)(hb + (size_t)s2 * FIN);
            vh v3 = *(const vh*)(hb + (size_t)s3 * FIN);
            vh v4 = *(const vh*)(hb + (size_t)s4 * FIN);
            vh v5 = *(const vh*)(hb + (size_t)s5 * FIN);
            vh v6 = *(const vh*)(hb + (size_t)s6 * FIN);
            vh v7 = *(const vh*)(hb + (size_t)s7 * FIN);
#pragma unroll
            for (int q = 0; q < PH; q++) {
                acc0[q] += (float)v0[q] + (float)v2[q];
                acc1[q] += (float)v1[q] + (float)v3[q];
                acc0[q] += (float)v4[q] + (float)v6[q];
                acc1[q] += (float)v5[q] + (float)v7[q];
            }
        }
        for (; j + 2 <= end; j += 2) {
            int s0 = eidx[j];
            int s1 = eidx[j + 1];
            vh v0 = *(const vh*)(hb + (size_t)s0 * FIN);
            vh v1 = *(const vh*)(hb + (size_t)s1 * FIN);
#pragma unroll
            for (int q = 0; q < PH; q++) { acc0[q] += (float)v0[q]; acc1[q] += (float)v1[q]; }
        }
        if (j < end) {
            vh v = *(const vh*)(hb + (size_t)eidx[j] * FIN);
#pragma unroll
            for (int q = 0; q < PH; q++) acc0[q] += (float)v[q];
        }

        vh sf = *(const vh*)(hb + (size_t)g * FIN);
        float* svn = &sv[slot * SVS + lane * PH];
#pragma unroll
        for (int q = 0; q < PH; q++) {
            float v = di * ((acc0[q] + acc1[q]) + (float)sf[q]) + bias[lane * PH + q];
            svn[q] = fmaxf(v, 0.f);      // relu
        }
    }
    __syncthreads();                     // sW loaded + sv written

    if (g < n) {
        const float* vn = &sv[slot * SVS];
        if constexpr (OUT_HALF) {
            // FOUT=32: lane owns 4 output cols
            constexpr int PC = FOUT / L;
            float o[PC] = {};
            for (int k = 0; k < FIN; k++) {
                float vk = vn[k];
                float4 w = *(const float4*)&sW[k * FOUT + lane * PC];
                o[0] += vk * w.x; o[1] += vk * w.y; o[2] += vk * w.z; o[3] += vk * w.w;
            }
            union { __half h[4]; uint2 u; } pk;
#pragma unroll
            for (int q = 0; q < PC; q++) pk.h[q] = __float2half_rn(di * o[q]);
            *(uint2*)((__half*)outv + (size_t)g * FOUT + lane * PC) = pk.u;
        } else {
            // FOUT=2: lanes 0/1 each compute one fp32 output
            if (lane < FOUT) {
                float o = 0.f;
                for (int k = 0; k < FIN; k++) o += vn[k] * sW[k * FOUT + lane];
                ((float*)outv)[(size_t)g * FOUT + lane] = di * o;
            }
        }
    }
}

// fp32 scalar-gather agg for the final layer (F=2), bias, no relu
template <int F>
__global__ void agg_kernel(const int* __restrict__ eidx, const int* __restrict__ rowptr,
                           const float* __restrict__ dinv, const float* __restrict__ h,
                           const float* __restrict__ b, float* __restrict__ out, int n) {
    int g = (blockIdx.x * blockDim.x + threadIdx.x) / F;
    int lane = threadIdx.x % F;
    if (g >= n) return;
    int j = rowptr[g];
    int end = rowptr[g + 1];
    float di = dinv[g];
    float hs = h[(size_t)g * F + lane];

    float acc0 = 0.f, acc1 = 0.f, acc2 = 0.f, acc3 = 0.f;
    float acc4 = 0.f, acc5 = 0.f, acc6 = 0.f, acc7 = 0.f;
    for (; j + 8 <= end; j += 8) {
        int s0 = eidx[j];
        int s1 = eidx[j + 1];
        int s2 = eidx[j + 2];
        int s3 = eidx[j + 3];
        int s4 = eidx[j + 4];
        int s5 = eidx[j + 5];
        int s6 = eidx[j + 6];
        int s7 = eidx[j + 7];
        acc0 += h[(size_t)s0 * F + lane];
        acc1 += h[(size_t)s1 * F + lane];
        acc2 += h[(size_t)s2 * F + lane];
        acc3 += h[(size_t)s3 * F + lane];
        acc4 += h[(size_t)s4 * F + lane];
        acc5 += h[(size_t)s5 * F + lane];
        acc6 += h[(size_t)s6 * F + lane];
        acc7 += h[(size_t)s7 * F + lane];
    }
    for (; j + 2 <= end; j += 2) {
        int s0 = eidx[j];
        int s1 = eidx[j + 1];
        acc0 += h[(size_t)s0 * F + lane];
        acc1 += h[(size_t)s1 * F + lane];
    }
    if (j < end) {
        acc2 += h[(size_t)eidx[j] * F + lane];
    }
    float acc = ((acc0 + acc1) + (acc2 + acc3)) + ((acc4 + acc5) + (acc6 + acc7));
    out[(size_t)g * F + lane] = di * (acc + hs) + b[lane];
}

// ---------------------------------------------------------------------------
extern "C" void kernel_launch(void* const* d_in, const int* in_sizes, int n_in,
                              void* d_out, int out_size, void* d_ws, size_t ws_size,
                              hipStream_t stream) {
    const float* x  = (const float*)d_in[0];
    const int* ei   = (const int*)d_in[1];
    const float* W1 = (const float*)d_in[2];
    const float* b1 = (const float*)d_in[3];
    const float* W2 = (const float*)d_in[4];
    const float* b2 = (const float*)d_in[5];
    const float* W3 = (const float*)d_in[6];
    const float* b3 = (const float*)d_in[7];
    float* out = (float*)d_out;

    const int N = N_NODES;
    const int E = N_EDGES;
    const int* src = ei;
    const int* dst = ei + E;

    char* p = (char*)d_ws;
    int*    rowptr  = (int*)p;            p += ((size_t)(N + 1) * 4 + 15) / 16 * 16;
    float*  dinv    = (float*)p;          p += ((size_t)N * 4 + 15) / 16 * 16;
    int*    gbcount = (int*)p;            p += ((size_t)NBUCK * 4 + 15) / 16 * 16;
    int*    gbase   = (int*)p;            p += ((size_t)NBUCK * 4 + 15) / 16 * 16;
    int*    eidx    = (int*)p;            p += (size_t)E * 4;
    __half* A1      = (__half*)p;         p += (size_t)N * 64 * 2;
    __half* A2      = (__half*)p;         p += (size_t)N * 32 * 2;
    float*  A3      = (float*)p;          p += (size_t)N * 2 * 4;
    int*    bbuf    = (int*)p;            // 196*12288*4 = 9.6 MB (packed edges)

    const int T = 256;

    // --- build CSR + dinv: bucket -> scan196 -> fused hist/scan/scatter; sort ---
    hipMemsetAsync(gbcount, 0, NBUCK * sizeof(int), stream);
    bucket1_kernel<<<(E + 2047) / 2048, T, 0, stream>>>(src, dst, gbcount, bbuf, E);
    scan196_kernel<<<1, 256, 0, stream>>>(gbcount, gbase, rowptr + N, E);
    bucket2_kernel<<<NBUCK, 512, 0, stream>>>(bbuf, gbcount, gbase, rowptr, dinv, eidx, N);
    sortrow_wave<<<(N * 64 + T - 1) / T, T, 0, stream>>>(rowptr, eidx, N);

    // --- layer 1 GEMM: A1 = fp16(dinv * (x @ W1)) ---
    gemm_tiled<64, 64><<<(N + 63) / 64, T, 0, stream>>>(x, W1, dinv, A1, N);

    // --- fused agg1 + gemm2: A2 = fp16(dinv * relu(agg(A1)+b1) @ W2) ---
    agg_gemm_kernel<64, 32, true><<<(N + 31) / 32, T, 0, stream>>>(
        eidx, rowptr, dinv, A1, b1, W2, A2, N);

    // --- fused agg2 + gemm3: A3 = fp32(dinv * relu(agg(A2)+b2) @ W3) ---
    agg_gemm_kernel<32, 2, false><<<(N + 31) / 32, T, 0, stream>>>(
        eidx, rowptr, dinv, A2, b2, W3, A3, N);

    // --- final aggregation: out = dinv*(agg(A3)+self) + b3 ---
    agg_kernel<2><<<(N * 2 + T - 1) / T, T, 0, stream>>>(eidx, rowptr, dinv, A3, b3, out, N);
}